// Round 5
// baseline (384.593 us; speedup 1.0000x reference)
//
#include <hip/hip_runtime.h>
#include <hip/hip_bf16.h>

typedef __bf16 bf16;
typedef __bf16 bf16x2 __attribute__((ext_vector_type(2)));
typedef __bf16 bf16x4 __attribute__((ext_vector_type(4)));
typedef __bf16 bf16x8 __attribute__((ext_vector_type(8)));
typedef float f32x4 __attribute__((ext_vector_type(4)));
typedef float f32x16 __attribute__((ext_vector_type(16)));

#define MFMA16(A, B, C) __builtin_amdgcn_mfma_f32_16x16x32_bf16((A), (B), (C), 0, 0, 0)
#define MFMA32(A, B, C) __builtin_amdgcn_mfma_f32_32x32x16_bf16((A), (B), (C), 0, 0, 0)

__device__ __forceinline__ void gload_lds16(const void* g, void* l) {
  __builtin_amdgcn_global_load_lds(
      (const __attribute__((address_space(1))) void*)g,
      (__attribute__((address_space(3))) void*)l, 16, 0, 0);
}

__device__ __forceinline__ unsigned pk2(float a, float b) {
  bf16x2 t = {(bf16)a, (bf16)b};
  return __builtin_bit_cast(unsigned, t);
}

// ---------------- fused f32->bf16 casts (x, Wq, Wkv, Wo) ----------------
__global__ void cast_all_k(const float* __restrict__ x, const float* __restrict__ Wq,
                           const float* __restrict__ Wkv, const float* __restrict__ Wo,
                           bf16* __restrict__ xb, bf16* __restrict__ Wqb,
                           bf16* __restrict__ Wkvb, bf16* __restrict__ Wob) {
  int i = blockIdx.x * blockDim.x + threadIdx.x;  // 4,456,448 float4 units
  const float* s;
  bf16* d;
  int off;
  if (i < 2097152) { s = x; d = xb; off = i; }
  else if (i < 3145728) { s = Wq; d = Wqb; off = i - 2097152; }
  else if (i < 3407872) { s = Wkv; d = Wkvb; off = i - 3145728; }
  else { s = Wo; d = Wob; off = i - 3407872; }
  float4 v = ((const float4*)s)[off];
  bf16x4 o = {(bf16)v.x, (bf16)v.y, (bf16)v.z, (bf16)v.w};
  ((bf16x4*)d)[off] = o;
}

// ---------------- RoPE table ----------------
__global__ void rope_table_k(float* __restrict__ cosT, float* __restrict__ sinT) {
  int tid = blockIdx.x * blockDim.x + threadIdx.x;  // S*64
  int s = tid >> 6, i = tid & 63;
  float inv = exp2f(-(float)i * (19.931568569324174f / 64.0f));  // 1e6^(-i/64)
  float ang = (float)s * inv;
  cosT[tid] = cosf(ang);
  sinT[tid] = sinf(ang);
}

// ---------------- fused RoPE(Q), RoPE(K), V-transpose ----------------
__global__ void rope_all_k(const bf16* __restrict__ Qlin, const bf16* __restrict__ KVlin,
                           const float* __restrict__ cosT, const float* __restrict__ sinT,
                           bf16* __restrict__ Qr, bf16* __restrict__ Kr,
                           bf16* __restrict__ Vt) {
  int tid = blockIdx.x * blockDim.x + threadIdx.x;  // 5,767,168
  if (tid < 4194304) {  // rope Q
    int i = tid & 63;
    int h = (tid >> 6) & 15;
    int s = (tid >> 10) & 2047;
    int b = tid >> 21;
    const bf16* src = Qlin + ((size_t)(b * 2048 + s)) * 2048 + h * 128;
    float x1 = (float)src[i], x2 = (float)src[i + 64];
    float c = cosT[s * 64 + i], sn = sinT[s * 64 + i];
    bf16* dst = Qr + ((size_t)((b * 16 + h) * 2048 + s)) * 128;
    dst[i] = (bf16)(x1 * c - x2 * sn);
    dst[i + 64] = (bf16)(x2 * c + x1 * sn);
  } else if (tid < 4718592) {  // rope K
    int t = tid - 4194304;
    int i = t & 63;
    int kvh = (t >> 6) & 1;
    int s = (t >> 7) & 2047;
    int b = t >> 18;
    const bf16* src = KVlin + ((size_t)(b * 2048 + s)) * 512 + kvh * 128;
    float x1 = (float)src[i], x2 = (float)src[i + 64];
    float c = cosT[s * 64 + i], sn = sinT[s * 64 + i];
    bf16* dst = Kr + ((size_t)((b * 2 + kvh) * 2048 + s)) * 128;
    dst[i] = (bf16)(x1 * c - x2 * sn);
    dst[i + 64] = (bf16)(x2 * c + x1 * sn);
  } else {  // V transpose -> [B,KVH,128,S]
    int t = tid - 4718592;
    int s = t & 2047;
    int d = (t >> 11) & 127;
    int kvh = (t >> 18) & 1;
    int b = t >> 19;
    Vt[t] = KVlin[((size_t)(b * 2048 + s)) * 512 + 256 + kvh * 128 + d];
  }
}

// ---------------- BT GEMM: C[M,N] = A[M,K] * B[N,K]^T (+bias); BM = MI*32 ----------------
template <int MI, typename OutT>
__global__ __launch_bounds__(256) void gemm_bt_k(
    const bf16* __restrict__ A, const bf16* __restrict__ Bm,
    const float* __restrict__ bias, OutT* __restrict__ C, int M, int N, int K) {
  __shared__ __align__(16) bf16 As[MI * 32 * 64];
  __shared__ __align__(16) bf16 Bs[128 * 64];
  const int tid = threadIdx.x;
  const int lane = tid & 63;
  const int w = tid >> 6;
  const int wr = w >> 1, wc = w & 1;
  const size_t bm = (size_t)blockIdx.y * (MI * 32);
  const size_t bn = (size_t)blockIdx.x * 128;
  const int l8r = lane >> 3, l8c = lane & 7;

  f32x4 acc[MI][4] = {};

  for (int k0 = 0; k0 < K; k0 += 64) {
#pragma unroll
    for (int i = 0; i < MI; ++i) {
      int c = w * MI + i;
      int row = c * 8 + l8r;
      gload_lds16(A + (bm + row) * (size_t)K + k0 + l8c * 8, (char*)As + c * 1024);
    }
#pragma unroll
    for (int i = 0; i < 4; ++i) {
      int c = w * 4 + i;
      int row = c * 8 + l8r;
      gload_lds16(Bm + (bn + row) * (size_t)K + k0 + l8c * 8, (char*)Bs + c * 1024);
    }
    __syncthreads();
#pragma unroll
    for (int kk = 0; kk < 2; ++kk) {
      bf16x8 af[MI], bfr[4];
#pragma unroll
      for (int mi = 0; mi < MI; ++mi) {
        int r = wr * (MI * 16) + mi * 16 + (lane & 15);
        af[mi] = *(const bf16x8*)(As + r * 64 + kk * 32 + (lane >> 4) * 8);
      }
#pragma unroll
      for (int ni = 0; ni < 4; ++ni) {
        int r = wc * 64 + ni * 16 + (lane & 15);
        bfr[ni] = *(const bf16x8*)(Bs + r * 64 + kk * 32 + (lane >> 4) * 8);
      }
#pragma unroll
      for (int mi = 0; mi < MI; ++mi)
#pragma unroll
        for (int ni = 0; ni < 4; ++ni)
          acc[mi][ni] = MFMA16(af[mi], bfr[ni], acc[mi][ni]);
    }
    __syncthreads();
  }
#pragma unroll
  for (int mi = 0; mi < MI; ++mi) {
#pragma unroll
    for (int ni = 0; ni < 4; ++ni) {
      int col = (int)bn + wc * 64 + ni * 16 + (lane & 15);
      float bv = bias ? bias[col] : 0.0f;
#pragma unroll
      for (int j = 0; j < 4; ++j) {
        size_t row = bm + wr * (MI * 16) + mi * 16 + (lane >> 4) * 4 + j;
        C[row * N + col] = (OutT)(acc[mi][ni][j] + bv);
      }
    }
  }
}

// ---------------- Flash attention v4: 2-warp blocks, KVBLK=32, 4 blocks/CU ----------------
// Qr [B,H,S,128], Kr [B,KVH,S,128], Vt [B,KVH,128,S] -> O [B,S,H*128] (bf16)
// 1024 blocks x 128 thr; block = 64-row strip (warp w -> q [32w,32w+32)); dbuf 32KB LDS.
// Swapped QK (A=K,B=Q): lane softmax state for q=lane&31; PV rescale redistributed by shfl.
// Ks[bi]: [32 kv][128 d], granule(16B)-XOR by (row&7). Vs[bi]: 32 rows x 256B, row vr holds
// d = 4vr..4vr+3; granule g = 4*(kv>>3)+(d&3), slot = g ^ (vr&7).
__global__ __launch_bounds__(128, 2) void attn_k(
    const bf16* __restrict__ Qr, const bf16* __restrict__ Kr, const bf16* __restrict__ Vt,
    bf16* __restrict__ O) {
  __shared__ __align__(16) bf16 Ks[2][32 * 128];  // 2 x 8KB
  __shared__ __align__(16) bf16 Vs[2][32 * 128];  // 2 x 8KB

  const int S = 2048;
  const int lane = threadIdx.x & 63;
  const int w = threadIdx.x >> 6;  // 0..1
  const int h = lane >> 5;
  const int ql = lane & 31;

  // CU-balanced strip map: dispatch quadrants y give strips {a, 31-a, a+8, 23-a}
  const int bh = blockIdx.x & 31;
  const int a = (blockIdx.x >> 5) & 7;
  const int r4 = blockIdx.y;
  const int strip = (r4 == 0) ? a : (r4 == 1) ? (31 - a) : (r4 == 2) ? (a + 8) : (23 - a);

  const int b = bh >> 4, head = bh & 15;
  const int kvh = head >> 3;
  const bf16* Qbase = Qr + (size_t)bh * S * 128;
  const bf16* Kbase = Kr + (size_t)(b * 2 + kvh) * S * 128;
  const bf16* Vbase = Vt + (size_t)(b * 2 + kvh) * 128 * S;
  const float SCALE2 = 0.12751744f;  // (1/sqrt(128)) * log2(e)

  auto STAGE = [&](int bi, int t) {
#pragma unroll
    for (int i = 0; i < 4; ++i) {
      int c8 = w * 4 + i;  // 0..7
      {
        int row = c8 * 4 + (lane >> 4);  // 0..31
        int g = (lane & 15) ^ (row & 7);
        gload_lds16(Kbase + (size_t)(t * 32 + row) * 128 + g * 8, (char*)&Ks[bi][0] + c8 * 1024);
      }
      {
        int vr = c8 * 4 + (lane >> 4);  // 0..31
        int g = (lane & 15) ^ (vr & 7);
        int vd = 4 * vr + (g & 3);
        int vkv = 8 * (g >> 2);
        gload_lds16(Vbase + (size_t)vd * S + t * 32 + vkv, (char*)&Vs[bi][0] + c8 * 1024);
      }
    }
  };

  const int q0w = strip * 64 + w * 32;
  const int q_abs = q0w + ql;
  bf16x8 qf[8];
#pragma unroll
  for (int dc = 0; dc < 8; ++dc)
    qf[dc] = *(const bf16x8*)(Qbase + (size_t)q_abs * 128 + dc * 16 + 8 * h);

  f32x16 o_acc[4] = {};
  float m_run = -3.0e38f, l_run = 0.0f;
  const int nt = 2 * strip + 2;
  const int tmw = 2 * strip + w;

  STAGE(0, 0);
  __syncthreads();

  for (int t = 0; t < nt; ++t) {
    const int bi = t & 1;
    if (t + 1 < nt) STAGE(bi ^ 1, t + 1);

    if (t <= tmw) {
      const char* kb = (const char*)&Ks[bi][0];
      const char* vb = (const char*)&Vs[bi][0];

      // ---- QK^T (swapped): sa = S_raw[kv 0..31][q=ql] ----
      f32x16 sa = {};
      __builtin_amdgcn_s_setprio(1);
#pragma unroll
      for (int dc = 0; dc < 8; ++dc) {
        int koff = ql * 256 + (((2 * dc + h) ^ (ql & 7)) << 4);
        bf16x8 kf = *(const bf16x8*)(kb + koff);
        sa = MFMA32(kf, qf[dc], sa);
      }
      __builtin_amdgcn_s_setprio(0);

      // ---- causal mask (raw domain) + row max ----
      const bool full = (t * 32 + 31 <= q0w);
      float pm = -3.0e38f;
      if (full) {
#pragma unroll
        for (int r = 0; r < 16; ++r) pm = fmaxf(pm, sa[r]);
      } else {
#pragma unroll
        for (int r = 0; r < 16; ++r) {
          int kvr = t * 32 + (r & 3) + 8 * (r >> 2) + 4 * h;
          float v = (kvr > q_abs) ? -3.0e38f : sa[r];
          sa[r] = v;
          pm = fmaxf(pm, v);
        }
      }
      pm = fmaxf(pm, __shfl_xor(pm, 32, 64));
      pm *= SCALE2;  // scaled domain

      // ---- defer-max rescale (T13); corr redistributed to o_acc rows via shfl ----
      if (__any(pm - m_run > 11.5f)) {
        float mnew = fmaxf(m_run, pm);
        float corr = exp2f(m_run - mnew);
        m_run = mnew;
        l_run *= corr;
#pragma unroll
        for (int r = 0; r < 16; ++r) {
          float corr_r = __shfl(corr, (r & 3) + 8 * (r >> 2) + 4 * h, 64);
#pragma unroll
          for (int dt = 0; dt < 4; ++dt) o_acc[dt][r] *= corr_r;
        }
      }

      // ---- P = exp2(raw*SCALE2 - m), row sum ----
      float ts = 0.0f;
#pragma unroll
      for (int r = 0; r < 16; ++r) {
        float p = exp2f(fmaf(sa[r], SCALE2, -m_run));
        sa[r] = p;
        ts += p;
      }
      ts += __shfl_xor(ts, 32, 64);
      l_run += ts;

      // ---- pack P -> PV A-frags: pa[c] = P[q=ql][kv = c*16 + 8h + 0..7] ----
      bf16x8 pa[2];
#pragma unroll
      for (int c = 0; c < 2; ++c) {
        const int base = c * 8;
        unsigned lo0 = pk2(sa[base + 0], sa[base + 1]);
        unsigned lo1 = pk2(sa[base + 2], sa[base + 3]);
        unsigned hi0 = pk2(sa[base + 4], sa[base + 5]);
        unsigned hi1 = pk2(sa[base + 6], sa[base + 7]);
        unsigned k0 = h ? hi0 : lo0, k1 = h ? hi1 : lo1;
        unsigned s0 = h ? lo0 : hi0, s1 = h ? lo1 : hi1;
        unsigned r0 = __shfl_xor(s0, 32, 64);
        unsigned r1 = __shfl_xor(s1, 32, 64);
        uint4 wd;
        wd.x = h ? r0 : k0;
        wd.y = h ? r1 : k1;
        wd.z = h ? k0 : r0;
        wd.w = h ? k1 : r1;
        pa[c] = __builtin_bit_cast(bf16x8, wd);
      }

      // ---- PV: o_acc[dt] += P[q][kv] * V[kv][d = dt*32 + ql] ----
      __builtin_amdgcn_s_setprio(1);
#pragma unroll
      for (int c = 0; c < 2; ++c) {
#pragma unroll
        for (int dt = 0; dt < 4; ++dt) {
          int vr = dt * 8 + (ql >> 2);
          int slot = (4 * (2 * c + h) + (ql & 3)) ^ (vr & 7);
          bf16x8 vf = *(const bf16x8*)(vb + vr * 256 + slot * 16);
          o_acc[dt] = MFMA32(pa[c], vf, o_acc[dt]);
        }
      }
      __builtin_amdgcn_s_setprio(0);
    }
    __syncthreads();
  }

  // ---- epilogue: per-row 1/l via shfl ----
  float rl = 1.0f / l_run;
  bf16* Ob = O + ((size_t)b * S) * 2048 + head * 128;
#pragma unroll
  for (int r = 0; r < 16; ++r) {
    int q_o = (r & 3) + 8 * (r >> 2) + 4 * h;
    float rl_r = __shfl(rl, q_o, 64);
    int qrow = q0w + q_o;
#pragma unroll
    for (int dt = 0; dt < 4; ++dt) {
      Ob[(size_t)qrow * 2048 + dt * 32 + ql] = (bf16)(o_acc[dt][r] * rl_r);
    }
  }
}

// ---------------- launch ----------------
extern "C" void kernel_launch(void* const* d_in, const int* in_sizes, int n_in,
                              void* d_out, int out_size, void* d_ws, size_t ws_size,
                              hipStream_t stream) {
  const float* x   = (const float*)d_in[0];
  // d_in[1] = attn_mask (pure causal; applied analytically in attn_k)
  const float* Wq  = (const float*)d_in[2];
  const float* bq  = (const float*)d_in[3];
  const float* Wkv = (const float*)d_in[4];
  const float* bkv = (const float*)d_in[5];
  const float* Wo  = (const float*)d_in[6];
  float* out = (float*)d_out;
  char* ws = (char*)d_ws;

  bf16* xb    = (bf16*)(ws + 0);
  bf16* Wqb   = (bf16*)(ws + 16777216);
  bf16* Wkvb  = (bf16*)(ws + 25165824);
  bf16* Wob   = (bf16*)(ws + 27262976);
  bf16* Qlin  = (bf16*)(ws + 35651584);
  bf16* KVlin = (bf16*)(ws + 52428800);
  bf16* Qrr   = (bf16*)(ws + 56623104);
  bf16* Krr   = (bf16*)(ws + 73400320);
  bf16* Vtt   = (bf16*)(ws + 75497472);
  bf16* Oat   = (bf16*)(ws + 77594624);
  float* cosT = (float*)(ws + 94371840);
  float* sinT = (float*)(ws + 94896128);

  cast_all_k<<<17408, 256, 0, stream>>>(x, Wq, Wkv, Wo, xb, Wqb, Wkvb, Wob);
  rope_table_k<<<512, 256, 0, stream>>>(cosT, sinT);

  gemm_bt_k<4, bf16><<<dim3(16, 32), 256, 0, stream>>>(xb, Wqb, bq, Qlin, 4096, 2048, 2048);
  gemm_bt_k<2, bf16><<<dim3(4, 64), 256, 0, stream>>>(xb, Wkvb, bkv, KVlin, 4096, 512, 2048);

  rope_all_k<<<22528, 256, 0, stream>>>(Qlin, KVlin, cosT, sinT, Qrr, Krr, Vtt);

  attn_k<<<dim3(256, 4), 128, 0, stream>>>(Qrr, Krr, Vtt, Oat);

  gemm_bt_k<4, float><<<dim3(16, 32), 256, 0, stream>>>(Oat, Wob, nullptr, out, 4096, 2048, 2048);
}

// Round 6
// 368.191 us; speedup vs baseline: 1.0445x; 1.0445x over previous
//
#include <hip/hip_runtime.h>
#include <hip/hip_bf16.h>

typedef __bf16 bf16;
typedef __bf16 bf16x2 __attribute__((ext_vector_type(2)));
typedef __bf16 bf16x4 __attribute__((ext_vector_type(4)));
typedef __bf16 bf16x8 __attribute__((ext_vector_type(8)));
typedef float f32x4 __attribute__((ext_vector_type(4)));
typedef float f32x16 __attribute__((ext_vector_type(16)));

#define MFMA16(A, B, C) __builtin_amdgcn_mfma_f32_16x16x32_bf16((A), (B), (C), 0, 0, 0)
#define MFMA32(A, B, C) __builtin_amdgcn_mfma_f32_32x32x16_bf16((A), (B), (C), 0, 0, 0)

__device__ __forceinline__ void gload_lds16(const void* g, void* l) {
  __builtin_amdgcn_global_load_lds(
      (const __attribute__((address_space(1))) void*)g,
      (__attribute__((address_space(3))) void*)l, 16, 0, 0);
}

__device__ __forceinline__ unsigned pk2(float a, float b) {
  bf16x2 t = {(bf16)a, (bf16)b};
  return __builtin_bit_cast(unsigned, t);
}

// ---------------- fused f32->bf16 casts (x, Wq, Wkv, Wo) ----------------
__global__ void cast_all_k(const float* __restrict__ x, const float* __restrict__ Wq,
                           const float* __restrict__ Wkv, const float* __restrict__ Wo,
                           bf16* __restrict__ xb, bf16* __restrict__ Wqb,
                           bf16* __restrict__ Wkvb, bf16* __restrict__ Wob) {
  int i = blockIdx.x * blockDim.x + threadIdx.x;  // 4,456,448 float4 units
  const float* s;
  bf16* d;
  int off;
  if (i < 2097152) { s = x; d = xb; off = i; }
  else if (i < 3145728) { s = Wq; d = Wqb; off = i - 2097152; }
  else if (i < 3407872) { s = Wkv; d = Wkvb; off = i - 3145728; }
  else { s = Wo; d = Wob; off = i - 3407872; }
  float4 v = ((const float4*)s)[off];
  bf16x4 o = {(bf16)v.x, (bf16)v.y, (bf16)v.z, (bf16)v.w};
  ((bf16x4*)d)[off] = o;
}

// ---------------- RoPE table ----------------
__global__ void rope_table_k(float* __restrict__ cosT, float* __restrict__ sinT) {
  int tid = blockIdx.x * blockDim.x + threadIdx.x;  // S*64
  int s = tid >> 6, i = tid & 63;
  float inv = exp2f(-(float)i * (19.931568569324174f / 64.0f));  // 1e6^(-i/64)
  float ang = (float)s * inv;
  cosT[tid] = cosf(ang);
  sinT[tid] = sinf(ang);
}

// ---------------- fused RoPE(Q), RoPE(K), V-transpose ----------------
__global__ void rope_all_k(const bf16* __restrict__ Qlin, const bf16* __restrict__ KVlin,
                           const float* __restrict__ cosT, const float* __restrict__ sinT,
                           bf16* __restrict__ Qr, bf16* __restrict__ Kr,
                           bf16* __restrict__ Vt) {
  int tid = blockIdx.x * blockDim.x + threadIdx.x;  // 5,767,168
  if (tid < 4194304) {  // rope Q
    int i = tid & 63;
    int h = (tid >> 6) & 15;
    int s = (tid >> 10) & 2047;
    int b = tid >> 21;
    const bf16* src = Qlin + ((size_t)(b * 2048 + s)) * 2048 + h * 128;
    float x1 = (float)src[i], x2 = (float)src[i + 64];
    float c = cosT[s * 64 + i], sn = sinT[s * 64 + i];
    bf16* dst = Qr + ((size_t)((b * 16 + h) * 2048 + s)) * 128;
    dst[i] = (bf16)(x1 * c - x2 * sn);
    dst[i + 64] = (bf16)(x2 * c + x1 * sn);
  } else if (tid < 4718592) {  // rope K
    int t = tid - 4194304;
    int i = t & 63;
    int kvh = (t >> 6) & 1;
    int s = (t >> 7) & 2047;
    int b = t >> 18;
    const bf16* src = KVlin + ((size_t)(b * 2048 + s)) * 512 + kvh * 128;
    float x1 = (float)src[i], x2 = (float)src[i + 64];
    float c = cosT[s * 64 + i], sn = sinT[s * 64 + i];
    bf16* dst = Kr + ((size_t)((b * 2 + kvh) * 2048 + s)) * 128;
    dst[i] = (bf16)(x1 * c - x2 * sn);
    dst[i + 64] = (bf16)(x2 * c + x1 * sn);
  } else {  // V transpose -> [B,KVH,128,S]
    int t = tid - 4718592;
    int s = t & 2047;
    int d = (t >> 11) & 127;
    int kvh = (t >> 18) & 1;
    int b = t >> 19;
    Vt[t] = KVlin[((size_t)(b * 2048 + s)) * 512 + 256 + kvh * 128 + d];
  }
}

// ---------------- BT GEMM: C[M,N] = A[M,K] * B[N,K]^T (+bias); BM = MI*32 ----------------
template <int MI, typename OutT>
__global__ __launch_bounds__(256) void gemm_bt_k(
    const bf16* __restrict__ A, const bf16* __restrict__ Bm,
    const float* __restrict__ bias, OutT* __restrict__ C, int M, int N, int K) {
  __shared__ __align__(16) bf16 As[MI * 32 * 64];
  __shared__ __align__(16) bf16 Bs[128 * 64];
  const int tid = threadIdx.x;
  const int lane = tid & 63;
  const int w = tid >> 6;
  const int wr = w >> 1, wc = w & 1;
  const size_t bm = (size_t)blockIdx.y * (MI * 32);
  const size_t bn = (size_t)blockIdx.x * 128;
  const int l8r = lane >> 3, l8c = lane & 7;

  f32x4 acc[MI][4] = {};

  for (int k0 = 0; k0 < K; k0 += 64) {
#pragma unroll
    for (int i = 0; i < MI; ++i) {
      int c = w * MI + i;
      int row = c * 8 + l8r;
      gload_lds16(A + (bm + row) * (size_t)K + k0 + l8c * 8, (char*)As + c * 1024);
    }
#pragma unroll
    for (int i = 0; i < 4; ++i) {
      int c = w * 4 + i;
      int row = c * 8 + l8r;
      gload_lds16(Bm + (bn + row) * (size_t)K + k0 + l8c * 8, (char*)Bs + c * 1024);
    }
    __syncthreads();
#pragma unroll
    for (int kk = 0; kk < 2; ++kk) {
      bf16x8 af[MI], bfr[4];
#pragma unroll
      for (int mi = 0; mi < MI; ++mi) {
        int r = wr * (MI * 16) + mi * 16 + (lane & 15);
        af[mi] = *(const bf16x8*)(As + r * 64 + kk * 32 + (lane >> 4) * 8);
      }
#pragma unroll
      for (int ni = 0; ni < 4; ++ni) {
        int r = wc * 64 + ni * 16 + (lane & 15);
        bfr[ni] = *(const bf16x8*)(Bs + r * 64 + kk * 32 + (lane >> 4) * 8);
      }
#pragma unroll
      for (int mi = 0; mi < MI; ++mi)
#pragma unroll
        for (int ni = 0; ni < 4; ++ni)
          acc[mi][ni] = MFMA16(af[mi], bfr[ni], acc[mi][ni]);
    }
    __syncthreads();
  }
#pragma unroll
  for (int mi = 0; mi < MI; ++mi) {
#pragma unroll
    for (int ni = 0; ni < 4; ++ni) {
      int col = (int)bn + wc * 64 + ni * 16 + (lane & 15);
      float bv = bias ? bias[col] : 0.0f;
#pragma unroll
      for (int j = 0; j < 4; ++j) {
        size_t row = bm + wr * (MI * 16) + mi * 16 + (lane >> 4) * 4 + j;
        C[row * N + col] = (OutT)(acc[mi][ni][j] + bv);
      }
    }
  }
}

// ---------------- Flash attention v5: 2-warp blocks, 64-row strips, KVBLK=64 ----------------
// Qr [B,H,S,128], Kr [B,KVH,S,128], Vt [B,KVH,128,S] -> O [B,S,H*128] (bf16)
// 1024 blocks x 128 thr; block = 64-row strip (warp w -> q [32w,32w+32)); nt = strip+1 tiles.
// Single-buffered K/V (32KB LDS -> 4 blocks/CU = 2 waves/SIMD) with skewed prefetch:
//   [QK(t)] bar [issue K(t+1)] [softmax] [PV(t)] bar [issue V(t+1)] -- each load covered
//   by ~half a tile of compute before the barrier that drains it (vmcnt(0) at barriers).
// Per-CU balance: strips {a, 31-a, (a+16)&31, (15-a)&31} on blocks c, c+256, c+512, c+768
// sum to 66 tiles for every a (assumes round-robin CU assignment; perf-only heuristic).
// Swapped QK (A=K,B=Q): per-lane softmax state for q=lane&31 (v3b-verified core).
__global__ __launch_bounds__(128, 2) void attn_k(
    const bf16* __restrict__ Qr, const bf16* __restrict__ Kr, const bf16* __restrict__ Vt,
    bf16* __restrict__ O) {
  __shared__ __align__(16) bf16 Ks[64 * 128];  // 16KB: [kv][d], 16B-granule XOR by row&7
  __shared__ __align__(16) bf16 Vs[128 * 64];  // 16KB: [d][kv], 16B-granule XOR by row&7

  const int S = 2048;
  const int tid = threadIdx.x;
  const int lane = tid & 63;
  const int w = tid >> 6;  // 0..1
  const int h = lane >> 5;
  const int ql = lane & 31;

  // strip/bh map: x = q*256 + c; a = c&31; bh = (q<<3)|(c>>5)
  const int x = blockIdx.x;
  const int q4 = x >> 8;
  const int c = x & 255;
  const int a = c & 31;
  const int strip = (q4 == 0) ? a : (q4 == 1) ? (31 - a)
                  : (q4 == 2) ? ((a + 16) & 31) : ((15 - a) & 31);
  const int bh = (q4 << 3) | (c >> 5);

  const int b = bh >> 4, head = bh & 15;
  const int kvh = head >> 3;
  const bf16* Qbase = Qr + (size_t)bh * S * 128;
  const bf16* Kbase = Kr + (size_t)(b * 2 + kvh) * S * 128;
  const bf16* Vbase = Vt + (size_t)(b * 2 + kvh) * 128 * S;
  const float SCALE2 = 0.12751744f;  // (1/sqrt(128)) * log2(e)

  auto STAGE_K = [&](int t) {
#pragma unroll
    for (int i = 0; i < 8; ++i) {
      int row = i * 8 + (tid >> 4);  // 0..63
      int g = (tid & 15) ^ (row & 7);
      gload_lds16(Kbase + (size_t)(t * 64 + row) * 128 + g * 8, (char*)Ks + i * 2048 + tid * 16);
    }
  };
  auto STAGE_V = [&](int t) {
#pragma unroll
    for (int i = 0; i < 8; ++i) {
      int vr = i * 16 + (tid >> 3);  // 0..127
      int g = (tid & 7) ^ (vr & 7);
      gload_lds16(Vbase + (size_t)vr * S + t * 64 + g * 8, (char*)Vs + i * 2048 + tid * 16);
    }
  };

  const int q0w = strip * 64 + w * 32;
  const int q_abs = q0w + ql;
  bf16x8 qf[8];  // Q row q_abs, d = dc*16 + 8h + 0..7
#pragma unroll
  for (int dc = 0; dc < 8; ++dc)
    qf[dc] = *(const bf16x8*)(Qbase + (size_t)q_abs * 128 + dc * 16 + 8 * h);

  f32x16 o_acc[4] = {};
  float m_run = -3.0e38f, l_run = 0.0f;

  STAGE_K(0);
  STAGE_V(0);
  __syncthreads();

  for (int t = 0; t <= strip; ++t) {
    const char* kb = (const char*)Ks;
    const char* vb = (const char*)Vs;

    // ---- QK^T (swapped): sa0 = S_raw[kv 0..31][q=ql], sa1 = [kv 32..63] ----
    f32x16 sa0 = {}, sa1 = {};
    __builtin_amdgcn_s_setprio(1);
#pragma unroll
    for (int dc = 0; dc < 8; ++dc) {
      int off = ql * 256 + (((2 * dc + h) ^ (ql & 7)) << 4);
      bf16x8 k0 = *(const bf16x8*)(kb + off);
      bf16x8 k1 = *(const bf16x8*)(kb + off + 32 * 256);
      sa0 = MFMA32(k0, qf[dc], sa0);
      sa1 = MFMA32(k1, qf[dc], sa1);
    }
    __builtin_amdgcn_s_setprio(0);

    __syncthreads();                   // all warps done reading Ks (drains prior V load too)
    if (t < strip) STAGE_K(t + 1);     // overwrite Ks; covered by softmax+PV below

    // ---- causal mask (raw domain) + row max ----
    const bool full = (t * 64 + 63 <= q0w);
    float pm = -3.0e38f;
    if (full) {
#pragma unroll
      for (int r = 0; r < 16; ++r) pm = fmaxf(pm, fmaxf(sa0[r], sa1[r]));
    } else {
#pragma unroll
      for (int r = 0; r < 16; ++r) {
        int kvr = t * 64 + (r & 3) + 8 * (r >> 2) + 4 * h;
        float v0 = (kvr > q_abs) ? -3.0e38f : sa0[r];
        float v1 = (kvr + 32 > q_abs) ? -3.0e38f : sa1[r];
        sa0[r] = v0;
        sa1[r] = v1;
        pm = fmaxf(pm, fmaxf(v0, v1));
      }
    }
    pm = fmaxf(pm, __shfl_xor(pm, 32, 64));
    pm *= SCALE2;  // scaled domain

    // ---- defer-max rescale (T13); corr redistributed to o_acc rows via shfl ----
    if (__any(pm - m_run > 11.5f)) {
      float mnew = fmaxf(m_run, pm);
      float corr = exp2f(m_run - mnew);
      m_run = mnew;
      l_run *= corr;
#pragma unroll
      for (int r = 0; r < 16; ++r) {
        float corr_r = __shfl(corr, (r & 3) + 8 * (r >> 2) + 4 * h, 64);
#pragma unroll
        for (int dt = 0; dt < 4; ++dt) o_acc[dt][r] *= corr_r;
      }
    }

    // ---- P = exp2(raw*SCALE2 - m), row sum (per-lane, q = ql) ----
    float ts = 0.0f;
#pragma unroll
    for (int r = 0; r < 16; ++r) {
      float p0 = exp2f(fmaf(sa0[r], SCALE2, -m_run));
      float p1 = exp2f(fmaf(sa1[r], SCALE2, -m_run));
      sa0[r] = p0;
      sa1[r] = p1;
      ts += p0 + p1;
    }
    ts += __shfl_xor(ts, 32, 64);
    l_run += ts;

    // ---- pack P -> PV A-frags: pa[cc] = P[q=ql][kv = cc*16 + 8h + 0..7] ----
    bf16x8 pa[4];
#pragma unroll
    for (int cc = 0; cc < 4; ++cc) {
      const f32x16& A = (cc < 2) ? sa0 : sa1;
      const int base = (cc & 1) * 8;
      unsigned lo0 = pk2(A[base + 0], A[base + 1]);
      unsigned lo1 = pk2(A[base + 2], A[base + 3]);
      unsigned hi0 = pk2(A[base + 4], A[base + 5]);
      unsigned hi1 = pk2(A[base + 6], A[base + 7]);
      unsigned k0 = h ? hi0 : lo0, k1 = h ? hi1 : lo1;
      unsigned s0 = h ? lo0 : hi0, s1 = h ? lo1 : hi1;
      unsigned r0 = __shfl_xor(s0, 32, 64);
      unsigned r1 = __shfl_xor(s1, 32, 64);
      uint4 wd;
      wd.x = h ? r0 : k0;
      wd.y = h ? r1 : k1;
      wd.z = h ? k0 : r0;
      wd.w = h ? k1 : r1;
      pa[cc] = __builtin_bit_cast(bf16x8, wd);
    }

    // ---- PV: o_acc[dt] += P[q][kv-chunk cc] * V[kv][d = dt*32 + ql] ----
    __builtin_amdgcn_s_setprio(1);
#pragma unroll
    for (int cc = 0; cc < 4; ++cc) {
#pragma unroll
      for (int dt = 0; dt < 4; ++dt) {
        int rd = dt * 32 + ql;
        int off = rd * 128 + (((2 * cc + h) ^ (ql & 7)) << 4);
        bf16x8 vf = *(const bf16x8*)(vb + off);
        o_acc[dt] = MFMA32(pa[cc], vf, o_acc[dt]);
      }
    }
    __builtin_amdgcn_s_setprio(0);

    __syncthreads();                   // all warps done reading Vs; drains K(t+1) load
    if (t < strip) STAGE_V(t + 1);     // overwrite Vs; covered by next tile's QK
  }

  // ---- epilogue: per-row 1/l via shfl ----
  float rl = 1.0f / l_run;
  bf16* Ob = O + ((size_t)b * S) * 2048 + head * 128;
#pragma unroll
  for (int r = 0; r < 16; ++r) {
    int q_o = (r & 3) + 8 * (r >> 2) + 4 * h;
    float rl_r = __shfl(rl, q_o, 64);
    int qrow = q0w + q_o;
#pragma unroll
    for (int dt = 0; dt < 4; ++dt) {
      Ob[(size_t)qrow * 2048 + dt * 32 + ql] = (bf16)(o_acc[dt][r] * rl_r);
    }
  }
}

// ---------------- launch ----------------
extern "C" void kernel_launch(void* const* d_in, const int* in_sizes, int n_in,
                              void* d_out, int out_size, void* d_ws, size_t ws_size,
                              hipStream_t stream) {
  const float* x   = (const float*)d_in[0];
  // d_in[1] = attn_mask (pure causal; applied analytically in attn_k)
  const float* Wq  = (const float*)d_in[2];
  const float* bq  = (const float*)d_in[3];
  const float* Wkv = (const float*)d_in[4];
  const float* bkv = (const float*)d_in[5];
  const float* Wo  = (const float*)d_in[6];
  float* out = (float*)d_out;
  char* ws = (char*)d_ws;

  bf16* xb    = (bf16*)(ws + 0);
  bf16* Wqb   = (bf16*)(ws + 16777216);
  bf16* Wkvb  = (bf16*)(ws + 25165824);
  bf16* Wob   = (bf16*)(ws + 27262976);
  bf16* Qlin  = (bf16*)(ws + 35651584);
  bf16* KVlin = (bf16*)(ws + 52428800);
  bf16* Qrr   = (bf16*)(ws + 56623104);
  bf16* Krr   = (bf16*)(ws + 73400320);
  bf16* Vtt   = (bf16*)(ws + 75497472);
  bf16* Oat   = (bf16*)(ws + 77594624);
  float* cosT = (float*)(ws + 94371840);
  float* sinT = (float*)(ws + 94896128);

  cast_all_k<<<17408, 256, 0, stream>>>(x, Wq, Wkv, Wo, xb, Wqb, Wkvb, Wob);
  rope_table_k<<<512, 256, 0, stream>>>(cosT, sinT);

  gemm_bt_k<4, bf16><<<dim3(16, 32), 256, 0, stream>>>(xb, Wqb, bq, Qlin, 4096, 2048, 2048);
  gemm_bt_k<2, bf16><<<dim3(4, 64), 256, 0, stream>>>(xb, Wkvb, bkv, KVlin, 4096, 512, 2048);

  rope_all_k<<<22528, 256, 0, stream>>>(Qlin, KVlin, cosT, sinT, Qrr, Krr, Vtt);

  attn_k<<<dim3(1024), 128, 0, stream>>>(Qrr, Krr, Vtt, Oat);

  gemm_bt_k<4, float><<<dim3(16, 32), 256, 0, stream>>>(Oat, Wob, nullptr, out, 4096, 2048, 2048);
}